// Round 1
// baseline (1588.545 us; speedup 1.0000x reference)
//
#include <hip/hip_runtime.h>

#define NN 50000
#define NE 800000
#define HD 128
#define INN 11
#define NL 4
#define NG16 3125        // 16-row node groups
#define BTS 132          // LDS K stride (shorts)
#define K1S 292          // nk1 K stride

typedef __attribute__((ext_vector_type(8))) short bf16x8;
typedef __attribute__((ext_vector_type(4))) float f32x4;

__device__ __forceinline__ float silu_f(float x) {
    return x * __builtin_amdgcn_rcpf(1.0f + __expf(-x));
}

__device__ __forceinline__ short f2bf(float x) {
    unsigned u = __float_as_uint(x);
    return (short)((u + 0x7FFFu + ((u >> 16) & 1u)) >> 16);
}
__device__ __forceinline__ unsigned f2bf2u(float lo, float hi) {
    unsigned a = __float_as_uint(lo), b = __float_as_uint(hi);
    a = (a + 0x7FFFu + ((a >> 16) & 1u)) >> 16;
    b = (b + 0x7FFFu + ((b >> 16) & 1u)) & 0xFFFF0000u;
    return a | b;
}
__device__ __forceinline__ bf16x8 pack8(float4 a, float4 b) {
    bf16x8 r;
    r[0] = f2bf(a.x); r[1] = f2bf(a.y); r[2] = f2bf(a.z); r[3] = f2bf(a.w);
    r[4] = f2bf(b.x); r[5] = f2bf(b.y); r[6] = f2bf(b.z); r[7] = f2bf(b.w);
    return r;
}

// ---------------- embedding ----------------
__global__ __launch_bounds__(256) void embed_kernel(
    const float* __restrict__ h0, const float* __restrict__ w,
    const float* __restrict__ b, float* __restrict__ h)
{
    int idx = blockIdx.x * 256 + threadIdx.x;
    if (idx >= NN * HD) return;
    int n = idx >> 7, j = idx & 127;
    float acc = b[j];
    #pragma unroll
    for (int k = 0; k < INN; ++k)
        acc += h0[n * INN + k] * w[k * HD + j];
    h[idx] = acc;
}

// ---------------- CSR build ----------------
__global__ __launch_bounds__(256) void csr_zero(int* __restrict__ cnt)
{
    int i = blockIdx.x * 256 + threadIdx.x;
    if (i < NN) cnt[i] = 0;
}

__global__ __launch_bounds__(256) void csr_hist(const int* __restrict__ ei, int* __restrict__ cnt)
{
    int e = blockIdx.x * 256 + threadIdx.x;
    atomicAdd(&cnt[ei[e]], 1);
}

__global__ __launch_bounds__(1024) void csr_scan(
    const int* __restrict__ cnt, int* __restrict__ rowptr, int* __restrict__ cursor)
{
    __shared__ int part[1024];
    int t = threadIdx.x;
    int base = t * 49;
    int s = 0;
    for (int i = 0; i < 49; ++i) { int j = base + i; if (j < NN) s += cnt[j]; }
    part[t] = s;
    __syncthreads();
    for (int off = 1; off < 1024; off <<= 1) {
        int v = (t >= off) ? part[t - off] : 0;
        __syncthreads();
        part[t] += v;
        __syncthreads();
    }
    int run = (t == 0) ? 0 : part[t - 1];
    for (int i = 0; i < 49; ++i) {
        int j = base + i;
        if (j < NN) { rowptr[j] = run; cursor[j] = run; run += cnt[j]; }
    }
    if (t == 1023) rowptr[NN] = part[1023];
}

__global__ __launch_bounds__(256) void csr_fill(
    const int* __restrict__ ei, int* __restrict__ cursor, int* __restrict__ eidx)
{
    int e = blockIdx.x * 256 + threadIdx.x;
    int r = ei[e];
    int p = atomicAdd(&cursor[r], 1);
    eidx[p] = e;
}

// ---------------- per-edge data, CSR order; ed = {r*64, c*64, rad, mask} ----------------
__global__ __launch_bounds__(256) void edge_pre(
    const int* __restrict__ ei, const int* __restrict__ eidx,
    const float* __restrict__ x, const float* __restrict__ eattr,
    const float* __restrict__ emask,
    int4* __restrict__ ed_p, float4* __restrict__ ea_p)
{
    int p = blockIdx.x * 256 + threadIdx.x;
    int e = eidx[p];
    int r = ei[e], c = ei[NE + e];
    float dx = x[3 * r]     - x[3 * c];
    float dy = x[3 * r + 1] - x[3 * c + 1];
    float dz = x[3 * r + 2] - x[3 * c + 2];
    float rad = dx * dx + dy * dy + dz * dz;
    ed_p[p] = make_int4(r * 64, c * 64, __float_as_int(rad), __float_as_int(emask[e]));
    ea_p[p] = ((const float4*)eattr)[e];
}

// ---------------- t|u = h @ ew1 halves (persistent MFMA, bf16 out) ----------------
__global__ __launch_bounds__(512) void tu_mfma(
    const float* __restrict__ h, const float* __restrict__ ew1_l,
    short* __restrict__ tb, short* __restrict__ ub)
{
    __shared__ __align__(16) short BT[128 * BTS];
    const float* wsrc = ew1_l + (blockIdx.y ? 128 * HD : 0);
    short* outp = blockIdx.y ? ub : tb;
    for (int i = threadIdx.x; i < 128 * 128; i += 512) {
        int c = i >> 7, k = i & 127;
        BT[c * BTS + k] = f2bf(wsrc[k * HD + c]);
    }
    int wv = threadIdx.x >> 6, lane = threadIdx.x & 63;
    int ln15 = lane & 15, quad = lane >> 4;
    __syncthreads();

    for (int g = blockIdx.x * 8 + wv; g < NG16; g += gridDim.x * 8) {
        int row = g * 16 + ln15;
        const float* hrow = h + row * HD;
        bf16x8 afr[4];
        #pragma unroll
        for (int kt = 0; kt < 4; ++kt) {
            float4 x0 = *(const float4*)(hrow + kt * 32 + quad * 8);
            float4 x1 = *(const float4*)(hrow + kt * 32 + quad * 8 + 4);
            afr[kt] = pack8(x0, x1);
        }
        #pragma unroll
        for (int ct = 0; ct < 8; ++ct) {
            f32x4 acc = {0.f, 0.f, 0.f, 0.f};
            #pragma unroll
            for (int kt = 0; kt < 4; ++kt) {
                bf16x8 bfr = *(const bf16x8*)&BT[(ct * 16 + ln15) * BTS + kt * 32 + quad * 8];
                acc = __builtin_amdgcn_mfma_f32_16x16x32_bf16(afr[kt], bfr, acc, 0, 0, 0);
            }
            int col = ct * 16 + ln15;
            #pragma unroll
            for (int r4 = 0; r4 < 4; ++r4) {
                int orow = g * 16 + quad * 4 + r4;
                outp[orow * HD + col] = f2bf(acc[r4]);
            }
        }
    }
}

// ---------------- node-aligned fused edge model: one node per wave, NO atomics ----------------
// v-phase split into pass1 (issue 16 ed_p loads -> 16 dependent ub gathers, results
// kept in regs) and pass2 (pure compute). pass1 for tile t+1 is issued right after
// tile t's A-fragments leave LDS, so the ~1000-cycle gather chain hides under the
// 32-MFMA + silu-agg phase of tile t.
__global__ __launch_bounds__(512, 4) void edge_m_kernel(
    const short* __restrict__ tb, const short* __restrict__ ub,
    const int4* __restrict__ ed_p, const float4* __restrict__ ea_p,
    const int* __restrict__ rowptr,
    const float* __restrict__ ew1_l, const float* __restrict__ eb1_l,
    const float* __restrict__ ew2_l, const float* __restrict__ eb2_l,
    float* __restrict__ agg)
{
    __shared__ __align__(16) short BT[128 * BTS];     // 33792 B (shared by 8 waves)
    __shared__ __align__(16) short VA[8][16 * BTS];   // 8 x 4224 B (per-wave private)
    __shared__ float s_b2[128];                       // ~68 KB -> 2 blocks/CU

    for (int i = threadIdx.x; i < 128 * 128; i += 512) {
        int k = i >> 7, n = i & 127;
        BT[n * BTS + k] = f2bf(ew2_l[i]);
    }
    if (threadIdx.x < 128) s_b2[threadIdx.x] = eb2_l[threadIdx.x];

    // per-thread column-pair constants (cols 2cp, 2cp+1)
    int cp = threadIdx.x & 63;
    int c0 = cp * 2;
    float wr0  = ew1_l[256 * HD + c0],     wr1  = ew1_l[256 * HD + c0 + 1];
    float wa00 = ew1_l[257 * HD + c0],     wa01 = ew1_l[257 * HD + c0 + 1];
    float wa10 = ew1_l[258 * HD + c0],     wa11 = ew1_l[258 * HD + c0 + 1];
    float wa20 = ew1_l[259 * HD + c0],     wa21 = ew1_l[259 * HD + c0 + 1];
    float wa30 = ew1_l[260 * HD + c0],     wa31 = ew1_l[260 * HD + c0 + 1];
    float b10  = eb1_l[c0],                b11  = eb1_l[c0 + 1];

    int lane = threadIdx.x & 63;
    int wv   = threadIdx.x >> 6;
    int ln15 = lane & 15;
    int quad = lane >> 4;
    short* VAw = &VA[wv][0];
    const unsigned* tb32 = (const unsigned*)tb;
    const unsigned* ub32 = (const unsigned*)ub;
    __syncthreads();   // BT ready (no further block syncs)

    for (int n = blockIdx.x * 8 + wv; n < NN; n += gridDim.x * 8) {
        int s = rowptr[n], en = rowptr[n + 1];
        unsigned tw = tb32[n * 64 + cp];       // this node's t row: loaded ONCE
        float t0 = __uint_as_float(tw << 16);
        float t1 = __uint_as_float(tw & 0xFFFF0000u);

        float sums[8];
        #pragma unroll
        for (int ct = 0; ct < 8; ++ct) sums[ct] = 0.f;

        // pipelined tile inputs (pass1 results)
        unsigned uwv[16];
        float    radv[16];

        // prologue: pass1 for first tile — all 16 gather chains in flight at once
        #pragma unroll
        for (int i = 0; i < 16; ++i) {
            int p = s + i;
            int4 ed = (p < en) ? ed_p[p] : make_int4(0, 0, 0, 0);
            radv[i] = __int_as_float(ed.z);
            uwv[i]  = ub32[ed.y + cp];         // ed.y==0 for pads: safe row-0 read
        }

        for (int base = s; base < en; base += 16) {
            // row masks for this lane's 4 rows (L1-hot: pass1 just touched these lines)
            int pr = base + quad * 4;
            float mk0 = (pr + 0 < en) ? __int_as_float(ed_p[pr + 0].w) : 0.f;
            float mk1 = (pr + 1 < en) ? __int_as_float(ed_p[pr + 1].w) : 0.f;
            float mk2 = (pr + 2 < en) ? __int_as_float(ed_p[pr + 2].w) : 0.f;
            float mk3 = (pr + 3 < en) ? __int_as_float(ed_p[pr + 3].w) : 0.f;

            // ---- pass2: pure compute from regs (ea_p loads independent/hoistable)
            #pragma unroll
            for (int i = 0; i < 16; ++i) {
                int p = base + i;
                unsigned out = 0u;
                if (p < en) {
                    float4 ea = ea_p[p];
                    float u0 = __uint_as_float(uwv[i] << 16);
                    float u1 = __uint_as_float(uwv[i] & 0xFFFF0000u);
                    float base0 = radv[i] * wr0 + ea.x * wa00 + ea.y * wa10 + ea.z * wa20 + ea.w * wa30 + b10;
                    float base1 = radv[i] * wr1 + ea.x * wa01 + ea.y * wa11 + ea.z * wa21 + ea.w * wa31 + b11;
                    out = f2bf2u(silu_f(t0 + u0 + base0), silu_f(t1 + u1 + base1));
                }
                *(unsigned*)&VAw[i * BTS + c0] = out;
            }

            __builtin_amdgcn_wave_barrier();       // VA writes above reads
            __builtin_amdgcn_s_waitcnt(0xc07f);    // lgkmcnt(0)

            bf16x8 afr[4];
            #pragma unroll
            for (int kt = 0; kt < 4; ++kt)
                afr[kt] = *(const bf16x8*)&VAw[ln15 * BTS + kt * 32 + quad * 8];

            __builtin_amdgcn_wave_barrier();       // reads above next-iter writes

            // ---- pass1 for NEXT tile: issue gather chains under the MFMA phase
            int nb = base + 16;
            if (nb < en) {
                #pragma unroll
                for (int i = 0; i < 16; ++i) {
                    int p = nb + i;
                    int4 ed = (p < en) ? ed_p[p] : make_int4(0, 0, 0, 0);
                    radv[i] = __int_as_float(ed.z);
                    uwv[i]  = ub32[ed.y + cp];
                }
            }

            #pragma unroll
            for (int ct = 0; ct < 8; ++ct) {
                f32x4 acc = {0.f, 0.f, 0.f, 0.f};
                #pragma unroll
                for (int kt = 0; kt < 4; ++kt) {
                    bf16x8 bfr = *(const bf16x8*)&BT[(ct * 16 + ln15) * BTS + kt * 32 + quad * 8];
                    acc = __builtin_amdgcn_mfma_f32_16x16x32_bf16(afr[kt], bfr, acc, 0, 0, 0);
                }
                float b2c = s_b2[ct * 16 + ln15];
                sums[ct] += silu_f(acc[0] + b2c) * mk0 + silu_f(acc[1] + b2c) * mk1
                          + silu_f(acc[2] + b2c) * mk2 + silu_f(acc[3] + b2c) * mk3;
            }
        }

        // cross-quad reduction: lanes {ln15, +16, +32, +48} hold partials for same col
        #pragma unroll
        for (int ct = 0; ct < 8; ++ct) {
            float v = sums[ct];
            v += __shfl_xor(v, 16, 64);
            v += __shfl_xor(v, 32, 64);
            sums[ct] = v;
        }
        // each lane stores 2 cols (constant-index select tree; no atomics)
        float vA = (quad & 2) ? ((quad & 1) ? sums[6] : sums[4])
                              : ((quad & 1) ? sums[2] : sums[0]);
        float vB = (quad & 2) ? ((quad & 1) ? sums[7] : sums[5])
                              : ((quad & 1) ? sums[3] : sums[1]);
        int colA = quad * 32 + ln15;
        agg[n * HD + colA]      = vA;
        agg[n * HD + colA + 16] = vB;
    }
}

// ---------------- node MLP layer 1 (persistent MFMA) ----------------
__global__ __launch_bounds__(512) void nk1_mfma(
    const float* __restrict__ h, const float* __restrict__ agg,
    const float* __restrict__ h0,
    const float* __restrict__ nw1_l, const float* __restrict__ nb1_l,
    short* __restrict__ qb)
{
    __shared__ __align__(16) short BT[64 * K1S];
    int c0 = blockIdx.y * 64;
    for (int i = threadIdx.x; i < 64 * 288; i += 512) {
        int c = i / 288, k = i - c * 288;
        BT[c * K1S + k] = (k < 267) ? f2bf(nw1_l[k * HD + c0 + c]) : (short)0;
    }
    int wv = threadIdx.x >> 6, lane = threadIdx.x & 63;
    int ln15 = lane & 15, quad = lane >> 4;
    __syncthreads();

    for (int g = blockIdx.x * 8 + wv; g < NG16; g += gridDim.x * 8) {
        int row = g * 16 + ln15;
        const float* hrow = h + row * HD;
        const float* arow = agg + row * HD;
        bf16x8 afr[9];
        #pragma unroll
        for (int kt = 0; kt < 4; ++kt) {
            float4 x0 = *(const float4*)(hrow + kt * 32 + quad * 8);
            float4 x1 = *(const float4*)(hrow + kt * 32 + quad * 8 + 4);
            afr[kt] = pack8(x0, x1);
        }
        #pragma unroll
        for (int kt = 0; kt < 4; ++kt) {
            float4 x0 = *(const float4*)(arow + kt * 32 + quad * 8);
            float4 x1 = *(const float4*)(arow + kt * 32 + quad * 8 + 4);
            afr[4 + kt] = pack8(x0, x1);
        }
        {
            bf16x8 a8 = {0, 0, 0, 0, 0, 0, 0, 0};
            if (quad == 0) {
                #pragma unroll
                for (int jj = 0; jj < 8; ++jj) a8[jj] = f2bf(h0[row * INN + jj]);
            } else if (quad == 1) {
                #pragma unroll
                for (int jj = 0; jj < 3; ++jj) a8[jj] = f2bf(h0[row * INN + 8 + jj]);
            }
            afr[8] = a8;
        }
        #pragma unroll
        for (int ct = 0; ct < 4; ++ct) {
            f32x4 acc = {0.f, 0.f, 0.f, 0.f};
            #pragma unroll
            for (int kt = 0; kt < 9; ++kt) {
                bf16x8 bfr = *(const bf16x8*)&BT[(ct * 16 + ln15) * K1S + kt * 32 + quad * 8];
                acc = __builtin_amdgcn_mfma_f32_16x16x32_bf16(afr[kt], bfr, acc, 0, 0, 0);
            }
            int col = c0 + ct * 16 + ln15;
            float b = nb1_l[col];
            #pragma unroll
            for (int r4 = 0; r4 < 4; ++r4) {
                int orow = g * 16 + quad * 4 + r4;
                qb[orow * HD + col] = f2bf(silu_f(acc[r4] + b));
            }
        }
    }
}

// ---------------- node MLP layer 2 + residual (persistent MFMA) ----------------
__global__ __launch_bounds__(512) void nk2_mfma(
    const short* __restrict__ qb, const float* __restrict__ nw2_l,
    const float* __restrict__ nb2_l, float* __restrict__ h)
{
    __shared__ __align__(16) short BT[128 * BTS];
    for (int i = threadIdx.x; i < 128 * 128; i += 512) {
        int c = i >> 7, k = i & 127;
        BT[c * BTS + k] = f2bf(nw2_l[k * HD + c]);
    }
    int wv = threadIdx.x >> 6, lane = threadIdx.x & 63;
    int ln15 = lane & 15, quad = lane >> 4;
    __syncthreads();

    for (int g = blockIdx.x * 8 + wv; g < NG16; g += gridDim.x * 8) {
        int row = g * 16 + ln15;
        bf16x8 afr[4];
        #pragma unroll
        for (int kt = 0; kt < 4; ++kt)
            afr[kt] = *(const bf16x8*)(qb + row * HD + kt * 32 + quad * 8);

        #pragma unroll
        for (int ct = 0; ct < 8; ++ct) {
            f32x4 acc = {0.f, 0.f, 0.f, 0.f};
            #pragma unroll
            for (int kt = 0; kt < 4; ++kt) {
                bf16x8 bfr = *(const bf16x8*)&BT[(ct * 16 + ln15) * BTS + kt * 32 + quad * 8];
                acc = __builtin_amdgcn_mfma_f32_16x16x32_bf16(afr[kt], bfr, acc, 0, 0, 0);
            }
            int col = ct * 16 + ln15;
            float b = nb2_l[col];
            #pragma unroll
            for (int r4 = 0; r4 < 4; ++r4) {
                int orow = g * 16 + quad * 4 + r4;
                h[orow * HD + col] += acc[r4] + b;
            }
        }
    }
}

extern "C" void kernel_launch(void* const* d_in, const int* in_sizes, int n_in,
                              void* d_out, int out_size, void* d_ws, size_t ws_size,
                              hipStream_t stream)
{
    const float* h0    = (const float*)d_in[0];
    const float* x     = (const float*)d_in[1];
    const int*   ei    = (const int*)d_in[2];
    const float* eattr = (const float*)d_in[3];
    const float* emask = (const float*)d_in[5];
    const float* emb_w = (const float*)d_in[7];
    const float* emb_b = (const float*)d_in[8];
    const float* ew1   = (const float*)d_in[9];
    const float* eb1   = (const float*)d_in[10];
    const float* ew2   = (const float*)d_in[11];
    const float* eb2   = (const float*)d_in[12];
    const float* nw1   = (const float*)d_in[13];
    const float* nb1   = (const float*)d_in[14];
    const float* nw2   = (const float*)d_in[15];
    const float* nb2   = (const float*)d_in[16];

    float* h = (float*)d_out;

    // workspace layout (~80 MB; d_ws >= 256 MiB)
    short*  tb     = (short*)d_ws;                         // NN*HD bf16
    short*  ub     = tb + (size_t)NN * HD;                 // NN*HD bf16
    float*  agg    = (float*)(ub + (size_t)NN * HD);       // NN*HD fp32
    short*  qb     = tb;                                   // alias (tb dead by nk1)
    int*    cnt    = (int*)(agg + (size_t)NN * HD);        // NN
    int*    rowptr = cnt + NN;                             // NN+1
    int*    cursor = rowptr + NN + 1;                      // NN
    int*    eidx   = cursor + NN;                          // NE
    int4*   ed_p   = (int4*)(eidx + NE + 1);               // NE int4
    float4* ea_p   = (float4*)(ed_p + NE);                 // NE float4

    csr_zero<<<(NN + 255) / 256, 256, 0, stream>>>(cnt);
    csr_hist<<<NE / 256, 256, 0, stream>>>(ei, cnt);
    csr_scan<<<1, 1024, 0, stream>>>(cnt, rowptr, cursor);
    csr_fill<<<NE / 256, 256, 0, stream>>>(ei, cursor, eidx);
    edge_pre<<<NE / 256, 256, 0, stream>>>(ei, eidx, x, eattr, emask, ed_p, ea_p);

    embed_kernel<<<(NN * HD + 255) / 256, 256, 0, stream>>>(h0, emb_w, emb_b, h);

    dim3 gtu(128, 2);
    dim3 gn1(128, 2);
    for (int l = 0; l < NL; ++l) {
        tu_mfma<<<gtu, 512, 0, stream>>>(h, ew1 + l * 261 * HD, tb, ub);
        edge_m_kernel<<<512, 512, 0, stream>>>(tb, ub, ed_p, ea_p, rowptr,
            ew1 + l * 261 * HD, eb1 + l * HD, ew2 + l * HD * HD, eb2 + l * HD, agg);
        nk1_mfma<<<gn1, 512, 0, stream>>>(h, agg, h0,
            nw1 + l * 267 * HD, nb1 + l * HD, qb);
        nk2_mfma<<<128, 512, 0, stream>>>(qb, nw2 + l * HD * HD, nb2 + l * HD, h);
    }
}

// Round 2
// 1558.911 us; speedup vs baseline: 1.0190x; 1.0190x over previous
//
#include <hip/hip_runtime.h>

#define NN 50000
#define NE 800000
#define HD 128
#define INN 11
#define NL 4
#define NG16 3125        // 16-row node groups
#define BTS 132          // LDS K stride (shorts)
#define K1S 292          // nk1 K stride

typedef __attribute__((ext_vector_type(8))) short bf16x8;
typedef __attribute__((ext_vector_type(4))) float f32x4;

__device__ __forceinline__ float silu_f(float x) {
    return x * __builtin_amdgcn_rcpf(1.0f + __expf(-x));
}

__device__ __forceinline__ short f2bf(float x) {
    unsigned u = __float_as_uint(x);
    return (short)((u + 0x7FFFu + ((u >> 16) & 1u)) >> 16);
}
__device__ __forceinline__ unsigned f2bf2u(float lo, float hi) {
    unsigned a = __float_as_uint(lo), b = __float_as_uint(hi);
    a = (a + 0x7FFFu + ((a >> 16) & 1u)) >> 16;
    b = (b + 0x7FFFu + ((b >> 16) & 1u)) & 0xFFFF0000u;
    return a | b;
}
__device__ __forceinline__ bf16x8 pack8(float4 a, float4 b) {
    bf16x8 r;
    r[0] = f2bf(a.x); r[1] = f2bf(a.y); r[2] = f2bf(a.z); r[3] = f2bf(a.w);
    r[4] = f2bf(b.x); r[5] = f2bf(b.y); r[6] = f2bf(b.z); r[7] = f2bf(b.w);
    return r;
}

// ---------------- embedding ----------------
__global__ __launch_bounds__(256) void embed_kernel(
    const float* __restrict__ h0, const float* __restrict__ w,
    const float* __restrict__ b, float* __restrict__ h)
{
    int idx = blockIdx.x * 256 + threadIdx.x;
    if (idx >= NN * HD) return;
    int n = idx >> 7, j = idx & 127;
    float acc = b[j];
    #pragma unroll
    for (int k = 0; k < INN; ++k)
        acc += h0[n * INN + k] * w[k * HD + j];
    h[idx] = acc;
}

// ---------------- CSR build ----------------
__global__ __launch_bounds__(256) void csr_zero(int* __restrict__ cnt)
{
    int i = blockIdx.x * 256 + threadIdx.x;
    if (i < NN) cnt[i] = 0;
}

__global__ __launch_bounds__(256) void csr_hist(const int* __restrict__ ei, int* __restrict__ cnt)
{
    int e = blockIdx.x * 256 + threadIdx.x;
    atomicAdd(&cnt[ei[e]], 1);
}

__global__ __launch_bounds__(1024) void csr_scan(
    const int* __restrict__ cnt, int* __restrict__ rowptr, int* __restrict__ cursor)
{
    __shared__ int part[1024];
    int t = threadIdx.x;
    int base = t * 49;
    int s = 0;
    for (int i = 0; i < 49; ++i) { int j = base + i; if (j < NN) s += cnt[j]; }
    part[t] = s;
    __syncthreads();
    for (int off = 1; off < 1024; off <<= 1) {
        int v = (t >= off) ? part[t - off] : 0;
        __syncthreads();
        part[t] += v;
        __syncthreads();
    }
    int run = (t == 0) ? 0 : part[t - 1];
    for (int i = 0; i < 49; ++i) {
        int j = base + i;
        if (j < NN) { rowptr[j] = run; cursor[j] = run; run += cnt[j]; }
    }
    if (t == 1023) rowptr[NN] = part[1023];
}

__global__ __launch_bounds__(256) void csr_fill(
    const int* __restrict__ ei, int* __restrict__ cursor, int* __restrict__ eidx)
{
    int e = blockIdx.x * 256 + threadIdx.x;
    int r = ei[e];
    int p = atomicAdd(&cursor[r], 1);
    eidx[p] = e;
}

// ---------------- per-edge data, CSR order; ed = {r*64, c*64, rad, mask} ----------------
__global__ __launch_bounds__(256) void edge_pre(
    const int* __restrict__ ei, const int* __restrict__ eidx,
    const float* __restrict__ x, const float* __restrict__ emask,
    int4* __restrict__ ed_p)
{
    int p = blockIdx.x * 256 + threadIdx.x;
    int e = eidx[p];
    int r = ei[e], c = ei[NE + e];
    float dx = x[3 * r]     - x[3 * c];
    float dy = x[3 * r + 1] - x[3 * c + 1];
    float dz = x[3 * r + 2] - x[3 * c + 2];
    float rad = dx * dx + dy * dy + dz * dz;
    ed_p[p] = make_int4(r * 64, c * 64, __float_as_int(rad), __float_as_int(emask[e]));
}

// zero the 16 slack rows of vbuf (once, before the layer loop)
__global__ __launch_bounds__(1024) void vpad_zero(unsigned* __restrict__ vb32)
{
    vb32[(size_t)NE * 64 + threadIdx.x] = 0u;
}

// ---------------- t|u = h @ ew1 halves (persistent MFMA, bf16 out) ----------------
__global__ __launch_bounds__(512) void tu_mfma(
    const float* __restrict__ h, const float* __restrict__ ew1_l,
    short* __restrict__ tb, short* __restrict__ ub)
{
    __shared__ __align__(16) short BT[128 * BTS];
    const float* wsrc = ew1_l + (blockIdx.y ? 128 * HD : 0);
    short* outp = blockIdx.y ? ub : tb;
    for (int i = threadIdx.x; i < 128 * 128; i += 512) {
        int c = i >> 7, k = i & 127;
        BT[c * BTS + k] = f2bf(wsrc[k * HD + c]);
    }
    int wv = threadIdx.x >> 6, lane = threadIdx.x & 63;
    int ln15 = lane & 15, quad = lane >> 4;
    __syncthreads();

    for (int g = blockIdx.x * 8 + wv; g < NG16; g += gridDim.x * 8) {
        int row = g * 16 + ln15;
        const float* hrow = h + row * HD;
        bf16x8 afr[4];
        #pragma unroll
        for (int kt = 0; kt < 4; ++kt) {
            float4 x0 = *(const float4*)(hrow + kt * 32 + quad * 8);
            float4 x1 = *(const float4*)(hrow + kt * 32 + quad * 8 + 4);
            afr[kt] = pack8(x0, x1);
        }
        #pragma unroll
        for (int ct = 0; ct < 8; ++ct) {
            f32x4 acc = {0.f, 0.f, 0.f, 0.f};
            #pragma unroll
            for (int kt = 0; kt < 4; ++kt) {
                bf16x8 bfr = *(const bf16x8*)&BT[(ct * 16 + ln15) * BTS + kt * 32 + quad * 8];
                acc = __builtin_amdgcn_mfma_f32_16x16x32_bf16(afr[kt], bfr, acc, 0, 0, 0);
            }
            int col = ct * 16 + ln15;
            #pragma unroll
            for (int r4 = 0; r4 < 4; ++r4) {
                int orow = g * 16 + quad * 4 + r4;
                outp[orow * HD + col] = f2bf(acc[r4]);
            }
        }
    }
}

// ---------------- edge v-compute: streaming, no LDS, no MFMA ----------------
// v[p][c] = silu(t[row][c] + u[col][c] + rad*wr[c] + ea.wa[c] + b1[c]), bf16.
// Lane handles col pair (2cp, 2cp+1); 4 edges per wave-iteration for load batching.
// High occupancy (no LDS, ~64 VGPR) lets TLP hide the L3 gather latency.
__global__ __launch_bounds__(512) void edge_v_kernel(
    const short* __restrict__ tb, const short* __restrict__ ub,
    const int4* __restrict__ ed_p, const int* __restrict__ eidx,
    const float* __restrict__ eattr,
    const float* __restrict__ ew1_l, const float* __restrict__ eb1_l,
    short* __restrict__ vbuf)
{
    int cp = threadIdx.x & 63;
    int c0 = cp * 2;
    float wr0  = ew1_l[256 * HD + c0],     wr1  = ew1_l[256 * HD + c0 + 1];
    float wa00 = ew1_l[257 * HD + c0],     wa01 = ew1_l[257 * HD + c0 + 1];
    float wa10 = ew1_l[258 * HD + c0],     wa11 = ew1_l[258 * HD + c0 + 1];
    float wa20 = ew1_l[259 * HD + c0],     wa21 = ew1_l[259 * HD + c0 + 1];
    float wa30 = ew1_l[260 * HD + c0],     wa31 = ew1_l[260 * HD + c0 + 1];
    float b10  = eb1_l[c0],                b11  = eb1_l[c0 + 1];

    const unsigned* tb32 = (const unsigned*)tb;
    const unsigned* ub32 = (const unsigned*)ub;
    const float4*   ea4  = (const float4*)eattr;
    unsigned*       vb32 = (unsigned*)vbuf;

    int w  = (blockIdx.x * 512 + threadIdx.x) >> 6;
    int nw = gridDim.x * 8;

    for (int p0 = w * 4; p0 < NE; p0 += nw * 4) {      // NE % 4 == 0
        int4 edv[4]; unsigned twv[4], uwv[4]; float4 eav[4];
        #pragma unroll
        for (int j = 0; j < 4; ++j) edv[j] = ed_p[p0 + j];
        #pragma unroll
        for (int j = 0; j < 4; ++j) {
            twv[j] = tb32[edv[j].x + cp];
            uwv[j] = ub32[edv[j].y + cp];
            eav[j] = ea4[eidx[p0 + j]];
        }
        #pragma unroll
        for (int j = 0; j < 4; ++j) {
            float rad = __int_as_float(edv[j].z);
            float t0 = __uint_as_float(twv[j] << 16);
            float t1 = __uint_as_float(twv[j] & 0xFFFF0000u);
            float u0 = __uint_as_float(uwv[j] << 16);
            float u1 = __uint_as_float(uwv[j] & 0xFFFF0000u);
            float s0 = t0 + u0 + rad * wr0 + eav[j].x * wa00 + eav[j].y * wa10
                     + eav[j].z * wa20 + eav[j].w * wa30 + b10;
            float s1 = t1 + u1 + rad * wr1 + eav[j].x * wa01 + eav[j].y * wa11
                     + eav[j].z * wa21 + eav[j].w * wa31 + b11;
            vb32[(size_t)(p0 + j) * 64 + cp] = f2bf2u(silu_f(s0), silu_f(s1));
        }
    }
}

// ---------------- edge MFMA + aggregation: wave per node, A-fragments from global ----------------
// LDS = BT only (34 KB) -> 4 blocks/CU -> ~100% occupancy ceiling. agg stored bf16.
__global__ __launch_bounds__(512) void edge_agg_kernel(
    const short* __restrict__ vbuf, const int4* __restrict__ ed_p,
    const int* __restrict__ rowptr,
    const float* __restrict__ ew2_l, const float* __restrict__ eb2_l,
    short* __restrict__ aggb)
{
    __shared__ __align__(16) short BT[128 * BTS];
    __shared__ float s_b2[128];

    for (int i = threadIdx.x; i < 128 * 128; i += 512) {
        int k = i >> 7, n = i & 127;
        BT[n * BTS + k] = f2bf(ew2_l[i]);
    }
    if (threadIdx.x < 128) s_b2[threadIdx.x] = eb2_l[threadIdx.x];

    int lane = threadIdx.x & 63;
    int wv   = threadIdx.x >> 6;
    int ln15 = lane & 15;
    int quad = lane >> 4;
    __syncthreads();

    for (int n = blockIdx.x * 8 + wv; n < NN; n += gridDim.x * 8) {
        int s = rowptr[n], en = rowptr[n + 1];

        float sums[8];
        #pragma unroll
        for (int ct = 0; ct < 8; ++ct) sums[ct] = 0.f;

        for (int base = s; base < en; base += 16) {
            // A-fragments straight from global vbuf (16 B/lane, contiguous)
            const short* vrow = vbuf + (size_t)(base + ln15) * HD + quad * 8;
            bf16x8 afr[4];
            #pragma unroll
            for (int kt = 0; kt < 4; ++kt)
                afr[kt] = *(const bf16x8*)(vrow + kt * 32);

            int pr = base + quad * 4;
            float mk0 = (pr + 0 < en) ? __int_as_float(ed_p[pr + 0].w) : 0.f;
            float mk1 = (pr + 1 < en) ? __int_as_float(ed_p[pr + 1].w) : 0.f;
            float mk2 = (pr + 2 < en) ? __int_as_float(ed_p[pr + 2].w) : 0.f;
            float mk3 = (pr + 3 < en) ? __int_as_float(ed_p[pr + 3].w) : 0.f;

            #pragma unroll
            for (int ct = 0; ct < 8; ++ct) {
                f32x4 acc = {0.f, 0.f, 0.f, 0.f};
                #pragma unroll
                for (int kt = 0; kt < 4; ++kt) {
                    bf16x8 bfr = *(const bf16x8*)&BT[(ct * 16 + ln15) * BTS + kt * 32 + quad * 8];
                    acc = __builtin_amdgcn_mfma_f32_16x16x32_bf16(afr[kt], bfr, acc, 0, 0, 0);
                }
                float b2c = s_b2[ct * 16 + ln15];
                sums[ct] += silu_f(acc[0] + b2c) * mk0 + silu_f(acc[1] + b2c) * mk1
                          + silu_f(acc[2] + b2c) * mk2 + silu_f(acc[3] + b2c) * mk3;
            }
        }

        // cross-quad reduction: lanes {ln15, +16, +32, +48} hold partials for same col
        #pragma unroll
        for (int ct = 0; ct < 8; ++ct) {
            float v = sums[ct];
            v += __shfl_xor(v, 16, 64);
            v += __shfl_xor(v, 32, 64);
            sums[ct] = v;
        }
        float vA = (quad & 2) ? ((quad & 1) ? sums[6] : sums[4])
                              : ((quad & 1) ? sums[2] : sums[0]);
        float vB = (quad & 2) ? ((quad & 1) ? sums[7] : sums[5])
                              : ((quad & 1) ? sums[3] : sums[1]);
        int colA = quad * 32 + ln15;
        aggb[(size_t)n * HD + colA]      = f2bf(vA);
        aggb[(size_t)n * HD + colA + 16] = f2bf(vB);
    }
}

// ---------------- node MLP layer 1 (persistent MFMA; agg already bf16) ----------------
__global__ __launch_bounds__(512) void nk1_mfma(
    const float* __restrict__ h, const short* __restrict__ aggb,
    const float* __restrict__ h0,
    const float* __restrict__ nw1_l, const float* __restrict__ nb1_l,
    short* __restrict__ qb)
{
    __shared__ __align__(16) short BT[64 * K1S];
    int c0 = blockIdx.y * 64;
    for (int i = threadIdx.x; i < 64 * 288; i += 512) {
        int c = i / 288, k = i - c * 288;
        BT[c * K1S + k] = (k < 267) ? f2bf(nw1_l[k * HD + c0 + c]) : (short)0;
    }
    int wv = threadIdx.x >> 6, lane = threadIdx.x & 63;
    int ln15 = lane & 15, quad = lane >> 4;
    __syncthreads();

    for (int g = blockIdx.x * 8 + wv; g < NG16; g += gridDim.x * 8) {
        int row = g * 16 + ln15;
        const float* hrow = h + row * HD;
        bf16x8 afr[9];
        #pragma unroll
        for (int kt = 0; kt < 4; ++kt) {
            float4 x0 = *(const float4*)(hrow + kt * 32 + quad * 8);
            float4 x1 = *(const float4*)(hrow + kt * 32 + quad * 8 + 4);
            afr[kt] = pack8(x0, x1);
        }
        #pragma unroll
        for (int kt = 0; kt < 4; ++kt)
            afr[4 + kt] = *(const bf16x8*)(aggb + (size_t)row * HD + kt * 32 + quad * 8);
        {
            bf16x8 a8 = {0, 0, 0, 0, 0, 0, 0, 0};
            if (quad == 0) {
                #pragma unroll
                for (int jj = 0; jj < 8; ++jj) a8[jj] = f2bf(h0[row * INN + jj]);
            } else if (quad == 1) {
                #pragma unroll
                for (int jj = 0; jj < 3; ++jj) a8[jj] = f2bf(h0[row * INN + 8 + jj]);
            }
            afr[8] = a8;
        }
        #pragma unroll
        for (int ct = 0; ct < 4; ++ct) {
            f32x4 acc = {0.f, 0.f, 0.f, 0.f};
            #pragma unroll
            for (int kt = 0; kt < 9; ++kt) {
                bf16x8 bfr = *(const bf16x8*)&BT[(ct * 16 + ln15) * K1S + kt * 32 + quad * 8];
                acc = __builtin_amdgcn_mfma_f32_16x16x32_bf16(afr[kt], bfr, acc, 0, 0, 0);
            }
            int col = c0 + ct * 16 + ln15;
            float b = nb1_l[col];
            #pragma unroll
            for (int r4 = 0; r4 < 4; ++r4) {
                int orow = g * 16 + quad * 4 + r4;
                qb[orow * HD + col] = f2bf(silu_f(acc[r4] + b));
            }
        }
    }
}

// ---------------- node MLP layer 2 + residual (persistent MFMA) ----------------
__global__ __launch_bounds__(512) void nk2_mfma(
    const short* __restrict__ qb, const float* __restrict__ nw2_l,
    const float* __restrict__ nb2_l, float* __restrict__ h)
{
    __shared__ __align__(16) short BT[128 * BTS];
    for (int i = threadIdx.x; i < 128 * 128; i += 512) {
        int c = i >> 7, k = i & 127;
        BT[c * BTS + k] = f2bf(nw2_l[k * HD + c]);
    }
    int wv = threadIdx.x >> 6, lane = threadIdx.x & 63;
    int ln15 = lane & 15, quad = lane >> 4;
    __syncthreads();

    for (int g = blockIdx.x * 8 + wv; g < NG16; g += gridDim.x * 8) {
        int row = g * 16 + ln15;
        bf16x8 afr[4];
        #pragma unroll
        for (int kt = 0; kt < 4; ++kt)
            afr[kt] = *(const bf16x8*)(qb + row * HD + kt * 32 + quad * 8);

        #pragma unroll
        for (int ct = 0; ct < 8; ++ct) {
            f32x4 acc = {0.f, 0.f, 0.f, 0.f};
            #pragma unroll
            for (int kt = 0; kt < 4; ++kt) {
                bf16x8 bfr = *(const bf16x8*)&BT[(ct * 16 + ln15) * BTS + kt * 32 + quad * 8];
                acc = __builtin_amdgcn_mfma_f32_16x16x32_bf16(afr[kt], bfr, acc, 0, 0, 0);
            }
            int col = ct * 16 + ln15;
            float b = nb2_l[col];
            #pragma unroll
            for (int r4 = 0; r4 < 4; ++r4) {
                int orow = g * 16 + quad * 4 + r4;
                h[orow * HD + col] += acc[r4] + b;
            }
        }
    }
}

extern "C" void kernel_launch(void* const* d_in, const int* in_sizes, int n_in,
                              void* d_out, int out_size, void* d_ws, size_t ws_size,
                              hipStream_t stream)
{
    const float* h0    = (const float*)d_in[0];
    const float* x     = (const float*)d_in[1];
    const int*   ei    = (const int*)d_in[2];
    const float* eattr = (const float*)d_in[3];
    const float* emask = (const float*)d_in[5];
    const float* emb_w = (const float*)d_in[7];
    const float* emb_b = (const float*)d_in[8];
    const float* ew1   = (const float*)d_in[9];
    const float* eb1   = (const float*)d_in[10];
    const float* ew2   = (const float*)d_in[11];
    const float* eb2   = (const float*)d_in[12];
    const float* nw1   = (const float*)d_in[13];
    const float* nb1   = (const float*)d_in[14];
    const float* nw2   = (const float*)d_in[15];
    const float* nb2   = (const float*)d_in[16];

    float* h = (float*)d_out;

    // workspace layout (~248 MiB of the 256 MiB d_ws)
    short*  tb     = (short*)d_ws;                          // NN*HD bf16
    short*  ub     = tb + (size_t)NN * HD;                  // NN*HD bf16
    short*  aggb   = ub + (size_t)NN * HD;                  // NN*HD bf16
    short*  vbuf   = aggb + (size_t)NN * HD;                // (NE+16)*HD bf16
    int4*   ed_p   = (int4*)(vbuf + (size_t)(NE + 16) * HD);// NE int4
    int*    rowptr = (int*)(ed_p + NE);                     // NN+1
    int*    cnt    = rowptr + NN + 1;                       // NN
    int*    cursor = cnt + NN;                              // NN
    int*    eidx   = cursor + NN;                           // NE
    short*  qb     = tb;                                    // alias (tb dead by nk1)

    csr_zero<<<(NN + 255) / 256, 256, 0, stream>>>(cnt);
    csr_hist<<<NE / 256, 256, 0, stream>>>(ei, cnt);
    csr_scan<<<1, 1024, 0, stream>>>(cnt, rowptr, cursor);
    csr_fill<<<NE / 256, 256, 0, stream>>>(ei, cursor, eidx);
    edge_pre<<<NE / 256, 256, 0, stream>>>(ei, eidx, x, emask, ed_p);
    vpad_zero<<<1, 1024, 0, stream>>>((unsigned*)vbuf);

    embed_kernel<<<(NN * HD + 255) / 256, 256, 0, stream>>>(h0, emb_w, emb_b, h);

    dim3 gtu(128, 2);
    dim3 gn1(128, 2);
    for (int l = 0; l < NL; ++l) {
        tu_mfma<<<gtu, 512, 0, stream>>>(h, ew1 + l * 261 * HD, tb, ub);
        edge_v_kernel<<<1024, 512, 0, stream>>>(tb, ub, ed_p, eidx, eattr,
            ew1 + l * 261 * HD, eb1 + l * HD, vbuf);
        edge_agg_kernel<<<1024, 512, 0, stream>>>(vbuf, ed_p, rowptr,
            ew2 + l * HD * HD, eb2 + l * HD, aggb);
        nk1_mfma<<<gn1, 512, 0, stream>>>(h, aggb, h0,
            nw1 + l * 267 * HD, nb1 + l * HD, qb);
        nk2_mfma<<<128, 512, 0, stream>>>(qb, nw2 + l * HD * HD, nb2 + l * HD, h);
    }
}

// Round 3
// 1450.873 us; speedup vs baseline: 1.0949x; 1.0745x over previous
//
#include <hip/hip_runtime.h>

#define NN 50000
#define NE 800000
#define HD 128
#define INN 11
#define NL 4
#define NG16 3125        // 16-row node groups
#define BTS 132          // LDS K stride (shorts)
#define K1S 292          // nk1 K stride
#define NB  196          // CSR scan blocks (196*256 >= NN)

typedef __attribute__((ext_vector_type(8))) short bf16x8;
typedef __attribute__((ext_vector_type(4))) float f32x4;
typedef __attribute__((ext_vector_type(2))) float f32x2;

__device__ __forceinline__ float silu_f(float x) {
    return x * __builtin_amdgcn_rcpf(1.0f + __expf(-x));
}

__device__ __forceinline__ short f2bf(float x) {
    unsigned u = __float_as_uint(x);
    return (short)((u + 0x7FFFu + ((u >> 16) & 1u)) >> 16);
}
__device__ __forceinline__ unsigned f2bf2u(float lo, float hi) {
    unsigned a = __float_as_uint(lo), b = __float_as_uint(hi);
    a = (a + 0x7FFFu + ((a >> 16) & 1u)) >> 16;
    b = (b + 0x7FFFu + ((b >> 16) & 1u)) & 0xFFFF0000u;
    return a | b;
}
__device__ __forceinline__ bf16x8 pack8(float4 a, float4 b) {
    bf16x8 r;
    r[0] = f2bf(a.x); r[1] = f2bf(a.y); r[2] = f2bf(a.z); r[3] = f2bf(a.w);
    r[4] = f2bf(b.x); r[5] = f2bf(b.y); r[6] = f2bf(b.z); r[7] = f2bf(b.w);
    return r;
}

// ---------------- embedding ----------------
__global__ __launch_bounds__(256) void embed_kernel(
    const float* __restrict__ h0, const float* __restrict__ w,
    const float* __restrict__ b, float* __restrict__ h)
{
    int idx = blockIdx.x * 256 + threadIdx.x;
    if (idx >= NN * HD) return;
    int n = idx >> 7, j = idx & 127;
    float acc = b[j];
    #pragma unroll
    for (int k = 0; k < INN; ++k)
        acc += h0[n * INN + k] * w[k * HD + j];
    h[idx] = acc;
}

// ---------------- CSR build ----------------
__global__ __launch_bounds__(256) void csr_zero(int* __restrict__ cnt)
{
    int i = blockIdx.x * 256 + threadIdx.x;
    if (i < NN) cnt[i] = 0;
}

__global__ __launch_bounds__(256) void csr_hist(const int* __restrict__ ei, int* __restrict__ cnt)
{
    int e = blockIdx.x * 256 + threadIdx.x;
    atomicAdd(&cnt[ei[e]], 1);
}

// phase 1: per-block sums of cnt
__global__ __launch_bounds__(256) void csr_blocksum(
    const int* __restrict__ cnt, int* __restrict__ bsum)
{
    __shared__ int red[4];
    int j = blockIdx.x * 256 + threadIdx.x;
    int v = (j < NN) ? cnt[j] : 0;
    #pragma unroll
    for (int off = 1; off < 64; off <<= 1) v += __shfl_xor(v, off, 64);
    int lane = threadIdx.x & 63, wv = threadIdx.x >> 6;
    if (lane == 0) red[wv] = v;
    __syncthreads();
    if (threadIdx.x == 0)
        bsum[blockIdx.x] = red[0] + red[1] + red[2] + red[3];
}

// phase 2: scan 196 partials (single small block), also writes rowptr[NN]
__global__ __launch_bounds__(256) void csr_scanpart(
    const int* __restrict__ bsum, int* __restrict__ boff, int* __restrict__ rowptr)
{
    __shared__ int part[256];
    int t = threadIdx.x;
    int v = (t < NB) ? bsum[t] : 0;
    part[t] = v;
    __syncthreads();
    #pragma unroll
    for (int off = 1; off < 256; off <<= 1) {
        int tmp = (t >= off) ? part[t - off] : 0;
        __syncthreads();
        part[t] += tmp;
        __syncthreads();
    }
    if (t < NB) boff[t] = part[t] - v;          // exclusive
    if (t == NB - 1) rowptr[NN] = part[t];      // total
}

// phase 3: per-block local exclusive scan + global offset -> rowptr/cursor
__global__ __launch_bounds__(256) void csr_emit(
    const int* __restrict__ cnt, const int* __restrict__ boff,
    int* __restrict__ rowptr, int* __restrict__ cursor)
{
    __shared__ int part[256];
    int t = threadIdx.x;
    int j = blockIdx.x * 256 + t;
    int v = (j < NN) ? cnt[j] : 0;
    part[t] = v;
    __syncthreads();
    #pragma unroll
    for (int off = 1; off < 256; off <<= 1) {
        int tmp = (t >= off) ? part[t - off] : 0;
        __syncthreads();
        part[t] += tmp;
        __syncthreads();
    }
    if (j < NN) {
        int r = boff[blockIdx.x] + part[t] - v;
        rowptr[j] = r;
        cursor[j] = r;
    }
}

__global__ __launch_bounds__(256) void csr_fill(
    const int* __restrict__ ei, int* __restrict__ cursor, int* __restrict__ eidx)
{
    int e = blockIdx.x * 256 + threadIdx.x;
    int r = ei[e];
    int p = atomicAdd(&cursor[r], 1);
    eidx[p] = e;
}

// ---------------- per-edge data, CSR order; ed = {r*64, c*64, rad, mask} ----------------
__global__ __launch_bounds__(256) void edge_pre(
    const int* __restrict__ ei, const int* __restrict__ eidx,
    const float* __restrict__ x, const float* __restrict__ emask,
    int4* __restrict__ ed_p)
{
    int p = blockIdx.x * 256 + threadIdx.x;
    int e = eidx[p];
    int r = ei[e], c = ei[NE + e];
    float dx = x[3 * r]     - x[3 * c];
    float dy = x[3 * r + 1] - x[3 * c + 1];
    float dz = x[3 * r + 2] - x[3 * c + 2];
    float rad = dx * dx + dy * dy + dz * dz;
    ed_p[p] = make_int4(r * 64, c * 64, __float_as_int(rad), __float_as_int(emask[e]));
}

// zero the 16 slack rows of vbuf (once, before the layer loop)
__global__ __launch_bounds__(1024) void vpad_zero(unsigned* __restrict__ vb32)
{
    vb32[(size_t)NE * 64 + threadIdx.x] = 0u;
}

// ---------------- t|u = h @ ew1 halves (persistent MFMA, bf16 out) ----------------
// y==0 (t half) folds the eb1 bias into the output: t' = t + b1.
__global__ __launch_bounds__(512) void tu_mfma(
    const float* __restrict__ h, const float* __restrict__ ew1_l,
    const float* __restrict__ eb1_l,
    short* __restrict__ tb, short* __restrict__ ub)
{
    __shared__ __align__(16) short BT[128 * BTS];
    const float* wsrc = ew1_l + (blockIdx.y ? 128 * HD : 0);
    short* outp = blockIdx.y ? ub : tb;
    for (int i = threadIdx.x; i < 128 * 128; i += 512) {
        int c = i >> 7, k = i & 127;
        BT[c * BTS + k] = f2bf(wsrc[k * HD + c]);
    }
    int wv = threadIdx.x >> 6, lane = threadIdx.x & 63;
    int ln15 = lane & 15, quad = lane >> 4;
    __syncthreads();

    for (int g = blockIdx.x * 8 + wv; g < NG16; g += gridDim.x * 8) {
        int row = g * 16 + ln15;
        const float* hrow = h + row * HD;
        bf16x8 afr[4];
        #pragma unroll
        for (int kt = 0; kt < 4; ++kt) {
            float4 x0 = *(const float4*)(hrow + kt * 32 + quad * 8);
            float4 x1 = *(const float4*)(hrow + kt * 32 + quad * 8 + 4);
            afr[kt] = pack8(x0, x1);
        }
        #pragma unroll
        for (int ct = 0; ct < 8; ++ct) {
            f32x4 acc = {0.f, 0.f, 0.f, 0.f};
            #pragma unroll
            for (int kt = 0; kt < 4; ++kt) {
                bf16x8 bfr = *(const bf16x8*)&BT[(ct * 16 + ln15) * BTS + kt * 32 + quad * 8];
                acc = __builtin_amdgcn_mfma_f32_16x16x32_bf16(afr[kt], bfr, acc, 0, 0, 0);
            }
            int col = ct * 16 + ln15;
            float bb = blockIdx.y ? 0.f : eb1_l[col];
            #pragma unroll
            for (int r4 = 0; r4 < 4; ++r4) {
                int orow = g * 16 + quad * 4 + r4;
                outp[orow * HD + col] = f2bf(acc[r4] + bb);
            }
        }
    }
}

// ---------------- edge v-compute: streaming, no LDS, no MFMA ----------------
// v[p][c] = silu(t'[row][c] + u[col][c] + rad*wr[c] + ea.wa[c]), bf16 (b1 folded in t').
// Lane handles col pair (2cp, 2cp+1) via f32x2 math (v_pk_fma_f32 candidates).
__global__ __launch_bounds__(512) void edge_v_kernel(
    const short* __restrict__ tb, const short* __restrict__ ub,
    const int4* __restrict__ ed_p, const int* __restrict__ eidx,
    const float* __restrict__ eattr,
    const float* __restrict__ ew1_l,
    short* __restrict__ vbuf)
{
    int cp = threadIdx.x & 63;
    int c0 = cp * 2;
    f32x2 wr2  = *(const f32x2*)&ew1_l[256 * HD + c0];
    f32x2 wa02 = *(const f32x2*)&ew1_l[257 * HD + c0];
    f32x2 wa12 = *(const f32x2*)&ew1_l[258 * HD + c0];
    f32x2 wa22 = *(const f32x2*)&ew1_l[259 * HD + c0];
    f32x2 wa32 = *(const f32x2*)&ew1_l[260 * HD + c0];

    const unsigned* tb32 = (const unsigned*)tb;
    const unsigned* ub32 = (const unsigned*)ub;
    const float4*   ea4  = (const float4*)eattr;
    unsigned*       vb32 = (unsigned*)vbuf;

    int w  = (blockIdx.x * 512 + threadIdx.x) >> 6;
    int nw = gridDim.x * 8;

    for (int p0 = w * 4; p0 < NE; p0 += nw * 4) {      // NE % 4 == 0
        int4 edv[4]; unsigned twv[4], uwv[4]; float4 eav[4];
        #pragma unroll
        for (int j = 0; j < 4; ++j) edv[j] = ed_p[p0 + j];
        #pragma unroll
        for (int j = 0; j < 4; ++j) {
            twv[j] = tb32[edv[j].x + cp];
            uwv[j] = ub32[edv[j].y + cp];
            eav[j] = ea4[eidx[p0 + j]];
        }
        #pragma unroll
        for (int j = 0; j < 4; ++j) {
            float rad = __int_as_float(edv[j].z);
            f32x2 s;
            s.x = __uint_as_float(twv[j] << 16)        + __uint_as_float(uwv[j] << 16);
            s.y = __uint_as_float(twv[j] & 0xFFFF0000u) + __uint_as_float(uwv[j] & 0xFFFF0000u);
            s += rad * wr2;
            s += eav[j].x * wa02;
            s += eav[j].y * wa12;
            s += eav[j].z * wa22;
            s += eav[j].w * wa32;
            vb32[(size_t)(p0 + j) * 64 + cp] = f2bf2u(silu_f(s.x), silu_f(s.y));
        }
    }
}

// ---------------- edge MFMA + aggregation: wave per node, A-fragments from global ----------------
// LDS = BT only (34 KB) -> 4 blocks/CU. agg stored bf16.
__global__ __launch_bounds__(512) void edge_agg_kernel(
    const short* __restrict__ vbuf, const int4* __restrict__ ed_p,
    const int* __restrict__ rowptr,
    const float* __restrict__ ew2_l, const float* __restrict__ eb2_l,
    short* __restrict__ aggb)
{
    __shared__ __align__(16) short BT[128 * BTS];
    __shared__ float s_b2[128];

    for (int i = threadIdx.x; i < 128 * 128; i += 512) {
        int k = i >> 7, n = i & 127;
        BT[n * BTS + k] = f2bf(ew2_l[i]);
    }
    if (threadIdx.x < 128) s_b2[threadIdx.x] = eb2_l[threadIdx.x];

    int lane = threadIdx.x & 63;
    int wv   = threadIdx.x >> 6;
    int ln15 = lane & 15;
    int quad = lane >> 4;
    __syncthreads();

    for (int n = blockIdx.x * 8 + wv; n < NN; n += gridDim.x * 8) {
        int s = rowptr[n], en = rowptr[n + 1];

        float sums[8];
        #pragma unroll
        for (int ct = 0; ct < 8; ++ct) sums[ct] = 0.f;

        for (int base = s; base < en; base += 16) {
            // A-fragments straight from global vbuf (16 B/lane, contiguous)
            const short* vrow = vbuf + (size_t)(base + ln15) * HD + quad * 8;
            bf16x8 afr[4];
            #pragma unroll
            for (int kt = 0; kt < 4; ++kt)
                afr[kt] = *(const bf16x8*)(vrow + kt * 32);

            int pr = base + quad * 4;
            float mk0 = (pr + 0 < en) ? __int_as_float(ed_p[pr + 0].w) : 0.f;
            float mk1 = (pr + 1 < en) ? __int_as_float(ed_p[pr + 1].w) : 0.f;
            float mk2 = (pr + 2 < en) ? __int_as_float(ed_p[pr + 2].w) : 0.f;
            float mk3 = (pr + 3 < en) ? __int_as_float(ed_p[pr + 3].w) : 0.f;

            #pragma unroll
            for (int ct = 0; ct < 8; ++ct) {
                f32x4 acc = {0.f, 0.f, 0.f, 0.f};
                #pragma unroll
                for (int kt = 0; kt < 4; ++kt) {
                    bf16x8 bfr = *(const bf16x8*)&BT[(ct * 16 + ln15) * BTS + kt * 32 + quad * 8];
                    acc = __builtin_amdgcn_mfma_f32_16x16x32_bf16(afr[kt], bfr, acc, 0, 0, 0);
                }
                float b2c = s_b2[ct * 16 + ln15];
                sums[ct] += silu_f(acc[0] + b2c) * mk0 + silu_f(acc[1] + b2c) * mk1
                          + silu_f(acc[2] + b2c) * mk2 + silu_f(acc[3] + b2c) * mk3;
            }
        }

        // cross-quad reduction: lanes {ln15, +16, +32, +48} hold partials for same col
        #pragma unroll
        for (int ct = 0; ct < 8; ++ct) {
            float v = sums[ct];
            v += __shfl_xor(v, 16, 64);
            v += __shfl_xor(v, 32, 64);
            sums[ct] = v;
        }
        float vA = (quad & 2) ? ((quad & 1) ? sums[6] : sums[4])
                              : ((quad & 1) ? sums[2] : sums[0]);
        float vB = (quad & 2) ? ((quad & 1) ? sums[7] : sums[5])
                              : ((quad & 1) ? sums[3] : sums[1]);
        int colA = quad * 32 + ln15;
        aggb[(size_t)n * HD + colA]      = f2bf(vA);
        aggb[(size_t)n * HD + colA + 16] = f2bf(vB);
    }
}

// ---------------- node MLP layer 1 (persistent MFMA; agg already bf16) ----------------
__global__ __launch_bounds__(512) void nk1_mfma(
    const float* __restrict__ h, const short* __restrict__ aggb,
    const float* __restrict__ h0,
    const float* __restrict__ nw1_l, const float* __restrict__ nb1_l,
    short* __restrict__ qb)
{
    __shared__ __align__(16) short BT[64 * K1S];
    int c0 = blockIdx.y * 64;
    for (int i = threadIdx.x; i < 64 * 288; i += 512) {
        int c = i / 288, k = i - c * 288;
        BT[c * K1S + k] = (k < 267) ? f2bf(nw1_l[k * HD + c0 + c]) : (short)0;
    }
    int wv = threadIdx.x >> 6, lane = threadIdx.x & 63;
    int ln15 = lane & 15, quad = lane >> 4;
    __syncthreads();

    for (int g = blockIdx.x * 8 + wv; g < NG16; g += gridDim.x * 8) {
        int row = g * 16 + ln15;
        const float* hrow = h + row * HD;
        bf16x8 afr[9];
        #pragma unroll
        for (int kt = 0; kt < 4; ++kt) {
            float4 x0 = *(const float4*)(hrow + kt * 32 + quad * 8);
            float4 x1 = *(const float4*)(hrow + kt * 32 + quad * 8 + 4);
            afr[kt] = pack8(x0, x1);
        }
        #pragma unroll
        for (int kt = 0; kt < 4; ++kt)
            afr[4 + kt] = *(const bf16x8*)(aggb + (size_t)row * HD + kt * 32 + quad * 8);
        {
            bf16x8 a8 = {0, 0, 0, 0, 0, 0, 0, 0};
            if (quad == 0) {
                #pragma unroll
                for (int jj = 0; jj < 8; ++jj) a8[jj] = f2bf(h0[row * INN + jj]);
            } else if (quad == 1) {
                #pragma unroll
                for (int jj = 0; jj < 3; ++jj) a8[jj] = f2bf(h0[row * INN + 8 + jj]);
            }
            afr[8] = a8;
        }
        #pragma unroll
        for (int ct = 0; ct < 4; ++ct) {
            f32x4 acc = {0.f, 0.f, 0.f, 0.f};
            #pragma unroll
            for (int kt = 0; kt < 9; ++kt) {
                bf16x8 bfr = *(const bf16x8*)&BT[(ct * 16 + ln15) * K1S + kt * 32 + quad * 8];
                acc = __builtin_amdgcn_mfma_f32_16x16x32_bf16(afr[kt], bfr, acc, 0, 0, 0);
            }
            int col = c0 + ct * 16 + ln15;
            float b = nb1_l[col];
            #pragma unroll
            for (int r4 = 0; r4 < 4; ++r4) {
                int orow = g * 16 + quad * 4 + r4;
                qb[orow * HD + col] = f2bf(silu_f(acc[r4] + b));
            }
        }
    }
}

// ---------------- node MLP layer 2 + residual (persistent MFMA) ----------------
__global__ __launch_bounds__(512) void nk2_mfma(
    const short* __restrict__ qb, const float* __restrict__ nw2_l,
    const float* __restrict__ nb2_l, float* __restrict__ h)
{
    __shared__ __align__(16) short BT[128 * BTS];
    for (int i = threadIdx.x; i < 128 * 128; i += 512) {
        int c = i >> 7, k = i & 127;
        BT[c * BTS + k] = f2bf(nw2_l[k * HD + c]);
    }
    int wv = threadIdx.x >> 6, lane = threadIdx.x & 63;
    int ln15 = lane & 15, quad = lane >> 4;
    __syncthreads();

    for (int g = blockIdx.x * 8 + wv; g < NG16; g += gridDim.x * 8) {
        int row = g * 16 + ln15;
        bf16x8 afr[4];
        #pragma unroll
        for (int kt = 0; kt < 4; ++kt)
            afr[kt] = *(const bf16x8*)(qb + row * HD + kt * 32 + quad * 8);

        #pragma unroll
        for (int ct = 0; ct < 8; ++ct) {
            f32x4 acc = {0.f, 0.f, 0.f, 0.f};
            #pragma unroll
            for (int kt = 0; kt < 4; ++kt) {
                bf16x8 bfr = *(const bf16x8*)&BT[(ct * 16 + ln15) * BTS + kt * 32 + quad * 8];
                acc = __builtin_amdgcn_mfma_f32_16x16x32_bf16(afr[kt], bfr, acc, 0, 0, 0);
            }
            int col = ct * 16 + ln15;
            float b = nb2_l[col];
            #pragma unroll
            for (int r4 = 0; r4 < 4; ++r4) {
                int orow = g * 16 + quad * 4 + r4;
                h[orow * HD + col] += acc[r4] + b;
            }
        }
    }
}

extern "C" void kernel_launch(void* const* d_in, const int* in_sizes, int n_in,
                              void* d_out, int out_size, void* d_ws, size_t ws_size,
                              hipStream_t stream)
{
    const float* h0    = (const float*)d_in[0];
    const float* x     = (const float*)d_in[1];
    const int*   ei    = (const int*)d_in[2];
    const float* eattr = (const float*)d_in[3];
    const float* emask = (const float*)d_in[5];
    const float* emb_w = (const float*)d_in[7];
    const float* emb_b = (const float*)d_in[8];
    const float* ew1   = (const float*)d_in[9];
    const float* eb1   = (const float*)d_in[10];
    const float* ew2   = (const float*)d_in[11];
    const float* eb2   = (const float*)d_in[12];
    const float* nw1   = (const float*)d_in[13];
    const float* nb1   = (const float*)d_in[14];
    const float* nw2   = (const float*)d_in[15];
    const float* nb2   = (const float*)d_in[16];

    float* h = (float*)d_out;

    // workspace layout (~248 MiB of the 256 MiB d_ws)
    short*  tb     = (short*)d_ws;                          // NN*HD bf16
    short*  ub     = tb + (size_t)NN * HD;                  // NN*HD bf16
    short*  aggb   = ub + (size_t)NN * HD;                  // NN*HD bf16
    short*  vbuf   = aggb + (size_t)NN * HD;                // (NE+16)*HD bf16
    int4*   ed_p   = (int4*)(vbuf + (size_t)(NE + 16) * HD);// NE int4
    int*    rowptr = (int*)(ed_p + NE);                     // NN+1
    int*    cnt    = rowptr + NN + 1;                       // NN
    int*    cursor = cnt + NN;                              // NN
    int*    eidx   = cursor + NN;                           // NE
    int*    bsum   = eidx + NE;                             // NB
    int*    boff   = bsum + NB;                             // NB
    short*  qb     = tb;                                    // alias (tb dead by nk1)

    csr_zero<<<(NN + 255) / 256, 256, 0, stream>>>(cnt);
    csr_hist<<<NE / 256, 256, 0, stream>>>(ei, cnt);
    csr_blocksum<<<NB, 256, 0, stream>>>(cnt, bsum);
    csr_scanpart<<<1, 256, 0, stream>>>(bsum, boff, rowptr);
    csr_emit<<<NB, 256, 0, stream>>>(cnt, boff, rowptr, cursor);
    csr_fill<<<NE / 256, 256, 0, stream>>>(ei, cursor, eidx);
    edge_pre<<<NE / 256, 256, 0, stream>>>(ei, eidx, x, emask, ed_p);
    vpad_zero<<<1, 1024, 0, stream>>>((unsigned*)vbuf);

    embed_kernel<<<(NN * HD + 255) / 256, 256, 0, stream>>>(h0, emb_w, emb_b, h);

    dim3 gtu(128, 2);
    dim3 gn1(128, 2);
    for (int l = 0; l < NL; ++l) {
        tu_mfma<<<gtu, 512, 0, stream>>>(h, ew1 + l * 261 * HD, eb1 + l * HD, tb, ub);
        edge_v_kernel<<<1024, 512, 0, stream>>>(tb, ub, ed_p, eidx, eattr,
            ew1 + l * 261 * HD, vbuf);
        edge_agg_kernel<<<1024, 512, 0, stream>>>(vbuf, ed_p, rowptr,
            ew2 + l * HD * HD, eb2 + l * HD, aggb);
        nk1_mfma<<<gn1, 512, 0, stream>>>(h, aggb, h0,
            nw1 + l * 267 * HD, nb1 + l * HD, qb);
        nk2_mfma<<<128, 512, 0, stream>>>(qb, nw2 + l * HD * HD, nb2 + l * HD, h);
    }
}